// Round 3
// baseline (1122.784 us; speedup 1.0000x reference)
//
#include <hip/hip_runtime.h>

// Problem constants
constexpr int kB  = 1024;
constexpr int kT  = 512;
constexpr int kF  = 32;
constexpr int kE  = 16;
constexpr int kH  = 128;
constexpr int kMB = 16;             // batches per block (MFMA M)
constexpr int kNMB = kB / kMB;      // 64 batch tiles
constexpr int kTc = 32;             // chunk length
constexpr int kNCh = kT / kTc;      // 16 chunks
constexpr int kTg = kTc / 2;        // t-steps per GEMM block
constexpr size_t kH0Str = (size_t)kB * kTc * kH;     // u32 per h0 chunk buffer
constexpr size_t kSlots = (size_t)kNMB * kTc * 512;  // gx lane-slots per chunk (OLD 512-tid space)
constexpr size_t kGx0Str = kSlots * 12;              // u32 per gx0 chunk buffer

typedef __attribute__((ext_vector_type(8))) _Float16 f16x8;
typedef __attribute__((ext_vector_type(4))) _Float16 f16x4;
typedef __attribute__((ext_vector_type(4))) float    f32x4;

#define MFMA16(a,b,c) __builtin_amdgcn_mfma_f32_16x16x32_f16(a,b,c,0,0,0)

__device__ __forceinline__ float sigm_hw(float x){
    float e = __builtin_amdgcn_exp2f(-1.442695041f * x);
    return __builtin_amdgcn_rcpf(1.0f + e);
}
__device__ __forceinline__ float tanh_hw(float x){
    float e = __builtin_amdgcn_exp2f(-2.885390082f * x);
    return fmaf(2.0f, __builtin_amdgcn_rcpf(1.0f + e), -1.0f);
}
__device__ __forceinline__ void splitF(float v, _Float16 &hi, _Float16 &lo){
    hi = (_Float16)v;
    lo = (_Float16)(v - (float)hi);
}
__device__ __forceinline__ f16x8 loadW8(const float* __restrict__ p){
    f16x8 r;
#pragma unroll
    for (int j=0;j<8;j++) r[j] = (_Float16)p[j];
    return r;
}
__device__ __forceinline__ unsigned short f2u(_Float16 h){ return __builtin_bit_cast(unsigned short, h); }
__device__ __forceinline__ _Float16 u2f(unsigned short u){ return __builtin_bit_cast(_Float16, u); }
__device__ __forceinline__ unsigned pack2(float a, float b){
    return (unsigned)f2u((_Float16)a) | ((unsigned)f2u((_Float16)b) << 16);
}
__device__ __forceinline__ float uf(unsigned u){ return __builtin_bit_cast(float, u); }
// LDS-only barrier: drains ds ops (lgkmcnt) but leaves global loads/stores in
// flight across the barrier. The compiler still inserts vmcnt waits before
// register USES of prefetched data; cross-launch ordering comes from
// kernel-dispatch boundaries.
__device__ __forceinline__ void bar_lds(){
    asm volatile("s_waitcnt lgkmcnt(0)\n\ts_barrier" ::: "memory");
}

// LDS: h planes row-major [m][k] (136 = 128 + 8 pad). Double buffered; one
// lgkm-barrier per step.
struct SRec {
    alignas(16) _Float16 hH[2][16][136];
    alignas(16) _Float16 hL[2][16][136];
    alignas(16) float hf[16][132];         // head scratch
    alignas(16) float hf2[16][132];
};
struct SGem {
    alignas(16) _Float16 aH[2][16][136];
    alignas(16) _Float16 aL[2][16][136];
};
union SU { SRec r; SGem g; };

struct G3 { uint4 r, z, n; };   // f32 gx0 slot (48B)
struct G2 { uint4 a; uint2 b; };// f16 gx1 slot (24B)

// ---------------------------------------------------------------------------
// 256 blocks x 256 threads (4 waves), pipeline roles per launch (c=-1..kNCh+1):
//   blocks   0..63 : layer-0 GRU chunk c           (the serial pole)
//   blocks 64..191 : gx1 GEMM for chunk c-1  AND  gx0 GEMM for chunk c+1
//   blocks 192..255: layer-1 GRU chunk c-2 (+head on last)
// W=4 restructure (round 3): each wave owns TWO 16-col gate tiles
// (cols 32w..32w+31). The A-fragments (h hi/lo planes) are shared by both
// tiles, so the per-CU LDS read convoy halves (32KB/step vs 64KB at W=8)
// while MFMA issue per SIMD is unchanged (48x5=240cy). Barrier participants
// halve (less lockstep skew). 1 wave/SIMD (amdgpu_waves_per_eu(1)) lifts the
// VGPR budget so the doubled weight set (~96 VGPR) fits unspilled.
// All global layouts stay in the OLD 512-tid slot space: new lane (w,l)
// consumes/produces old-tid slots 128w+l (tile A) and 128w+64+l (tile B).
// Per-element op order is preserved -> bit-identical numerics.
// ---------------------------------------------------------------------------
__attribute__((amdgpu_waves_per_eu(1)))
__global__ void __launch_bounds__(256) rnn_fused(
    const float* __restrict__ x, const int* __restrict__ tick,
    const float* __restrict__ embed,
    const float* __restrict__ Wih0, const float* __restrict__ Whh0,
    const float* __restrict__ bih0, const float* __restrict__ bhh0,
    const float* __restrict__ Wih1, const float* __restrict__ bih1,
    const float* __restrict__ Whh1, const float* __restrict__ bhh1,
    const float* __restrict__ hw1, const float* __restrict__ hb1,
    const float* __restrict__ hw2, const float* __restrict__ hb2,
    unsigned* __restrict__ h0seq, unsigned* __restrict__ gxA,
    unsigned* __restrict__ gxB, float* __restrict__ h1state,
    unsigned* __restrict__ gx0, float* __restrict__ out, int c)
{
    __shared__ SU sm;
    const int tid = threadIdx.x;
    const int w = tid >> 6, l = tid & 63, lm = l & 15, lq = l >> 4;
    const int iA = 32*w + lm, iB = iA + 16;        // owned gate/hidden columns
    const int clsA[3] = { iA, 128 + iA, 256 + iA };
    const int clsB[3] = { iB, 128 + iB, 256 + iB };

    if (blockIdx.x < 64) {
        // ================= layer-0 recurrence, chunk c =================
        if (c < 0 || c >= kNCh) return;
        SRec &S = sm.r;
        const int mb = blockIdx.x;
        unsigned* h0w = h0seq + (size_t)(c & 1) * kH0Str;
        const unsigned* g0 = gx0 + (size_t)(c & 1) * kGx0Str;

        f16x8 wvA[3][4], wvB[3][4];
#pragma unroll
        for (int T=0; T<3; T++)
#pragma unroll
            for (int kt=0; kt<4; kt++){
                wvA[T][kt] = loadW8(Whh0 + (size_t)clsA[T]*kH + kt*32 + lq*8);
                wvB[T][kt] = loadW8(Whh0 + (size_t)clsB[T]*kH + kt*32 + lq*8);
            }
        const float brA = bhh0[clsA[0]], bzA = bhh0[clsA[1]], bnA = bhh0[clsA[2]];
        const float brB = bhh0[clsB[0]], bzB = bhh0[clsB[1]], bnB = bhh0[clsB[2]];

        // state init via ownership (4 waves x 2 tiles cover 16x128 exactly)
        float hregA[4], hregB[4];
        if (c == 0){
#pragma unroll
            for (int q=0;q<4;q++){
                hregA[q]=0.f; hregB[q]=0.f;
                S.hH[0][lq*4+q][iA]=(_Float16)0.f; S.hL[0][lq*4+q][iA]=(_Float16)0.f;
                S.hH[0][lq*4+q][iB]=(_Float16)0.f; S.hL[0][lq*4+q][iB]=(_Float16)0.f;
            }
        } else {
            const unsigned* h0p = h0seq + (size_t)((c-1) & 1) * kH0Str;
#pragma unroll
            for (int q=0;q<4;q++){
                unsigned uA = h0p[((size_t)(mb*kTc + kTc-1)*16 + lq*4+q)*kH + iA];
                unsigned uB = h0p[((size_t)(mb*kTc + kTc-1)*16 + lq*4+q)*kH + iB];
                _Float16 hhA = u2f((unsigned short)(uA>>16)), hlA = u2f((unsigned short)uA);
                _Float16 hhB = u2f((unsigned short)(uB>>16)), hlB = u2f((unsigned short)uB);
                hregA[q] = (float)hhA + (float)hlA;
                hregB[q] = (float)hhB + (float)hlB;
                S.hH[0][lq*4+q][iA]=hhA; S.hL[0][lq*4+q][iA]=hlA;
                S.hH[0][lq*4+q][iB]=hhB; S.hL[0][lq*4+q][iB]=hlB;
            }
        }
        // gx0 stream (f32 r/z/n) for both tiles, 2-step prefetch
        const size_t s0 = (size_t)mb*kTc*512 + 128*w + l;   // old_tid slot, tile A
        const size_t s1 = s0 + 64;                          // tile B
        auto ld3 = [&](size_t slot){
            G3 g; const unsigned* p = g0 + slot*12;
            g.r = *(const uint4*)p; g.z = *(const uint4*)(p+4); g.n = *(const uint4*)(p+8);
            return g;
        };
        G3 cA = ld3(s0), cB = ld3(s1), nA = ld3(s0+512), nB = ld3(s1+512);
        bar_lds();

        int buf = 0;
        for (int tc=0; tc<kTc; tc++){
            const int nb = buf ^ 1;
            f16x8 aHf[4], aLf[4];
#pragma unroll
            for (int kt=0;kt<4;kt++){
                aHf[kt] = *(const f16x8*)&S.hH[buf][lm][kt*32 + lq*8];
                aLf[kt] = *(const f16x8*)&S.hL[buf][lm][kt*32 + lq*8];
            }
            f32x4 aRA={brA,brA,brA,brA}, aZA={bzA,bzA,bzA,bzA}, aNA={bnA,bnA,bnA,bnA};
            f32x4 aRB={brB,brB,brB,brB}, aZB={bzB,bzB,bzB,bzB}, aNB={bnB,bnB,bnB,bnB};
#pragma unroll
            for (int kt=0;kt<4;kt++){
                aRA=MFMA16(aHf[kt],wvA[0][kt],aRA); aRA=MFMA16(aLf[kt],wvA[0][kt],aRA);
                aZA=MFMA16(aHf[kt],wvA[1][kt],aZA); aZA=MFMA16(aLf[kt],wvA[1][kt],aZA);
                aNA=MFMA16(aHf[kt],wvA[2][kt],aNA); aNA=MFMA16(aLf[kt],wvA[2][kt],aNA);
                aRB=MFMA16(aHf[kt],wvB[0][kt],aRB); aRB=MFMA16(aLf[kt],wvB[0][kt],aRB);
                aZB=MFMA16(aHf[kt],wvB[1][kt],aZB); aZB=MFMA16(aLf[kt],wvB[1][kt],aZB);
                aNB=MFMA16(aHf[kt],wvB[2][kt],aNB); aNB=MFMA16(aLf[kt],wvB[2][kt],aNB);
            }
            unsigned pkA[4], pkB[4];
#pragma unroll
            for (int q=0;q<4;q++){
                const float rxA[4] = { uf(cA.r.x), uf(cA.r.y), uf(cA.r.z), uf(cA.r.w) };
                const float zxA[4] = { uf(cA.z.x), uf(cA.z.y), uf(cA.z.z), uf(cA.z.w) };
                const float nxA[4] = { uf(cA.n.x), uf(cA.n.y), uf(cA.n.z), uf(cA.n.w) };
                float r = sigm_hw(aRA[q] + rxA[q]);
                float z = sigm_hw(aZA[q] + zxA[q]);
                float n = tanh_hw(fmaf(r, aNA[q], nxA[q]));
                float h = fmaf(z, hregA[q]-n, n);
                hregA[q] = h;
                _Float16 hh,hl; splitF(h,hh,hl);
                S.hH[nb][lq*4+q][iA]=hh; S.hL[nb][lq*4+q][iA]=hl;
                pkA[q] = ((unsigned)f2u(hh)<<16) | f2u(hl);
            }
#pragma unroll
            for (int q=0;q<4;q++){
                const float rxB[4] = { uf(cB.r.x), uf(cB.r.y), uf(cB.r.z), uf(cB.r.w) };
                const float zxB[4] = { uf(cB.z.x), uf(cB.z.y), uf(cB.z.z), uf(cB.z.w) };
                const float nxB[4] = { uf(cB.n.x), uf(cB.n.y), uf(cB.n.z), uf(cB.n.w) };
                float r = sigm_hw(aRB[q] + rxB[q]);
                float z = sigm_hw(aZB[q] + zxB[q]);
                float n = tanh_hw(fmaf(r, aNB[q], nxB[q]));
                float h = fmaf(z, hregB[q]-n, n);
                hregB[q] = h;
                _Float16 hh,hl; splitF(h,hh,hl);
                S.hH[nb][lq*4+q][iB]=hh; S.hL[nb][lq*4+q][iB]=hl;
                pkB[q] = ((unsigned)f2u(hh)<<16) | f2u(hl);
            }
#pragma unroll
            for (int q=0;q<4;q++){
                h0w[((size_t)(mb*kTc + tc)*16 + lq*4+q)*kH + iA] = pkA[q];
                h0w[((size_t)(mb*kTc + tc)*16 + lq*4+q)*kH + iB] = pkB[q];
            }
            cA = nA; cB = nB;
            int tn = tc + 2; if (tn > kTc-1) tn = kTc-1;
            nA = ld3(s0 + (size_t)tn*512);
            nB = ld3(s1 + (size_t)tn*512);
            bar_lds();
            buf = nb;
        }
    } else if (blockIdx.x < 192) {
        // ============ gx GEMM blocks: gx1 for c-1, then gx0 for c+1 ============
        const int bid = blockIdx.x - 64;
        const int mb = bid >> 1, t0 = (bid & 1) * kTg;
        const int b0 = mb * kMB;
        const int g = c - 1;
        if (g >= 0 && g < kNCh) {
            SGem &S = sm.g;
            const unsigned* h0r = h0seq + (size_t)(g & 1) * kH0Str;
            unsigned* gA = gxA + (size_t)(g & 1) * kSlots * 4;
            unsigned* gB = gxB + (size_t)(g & 1) * kSlots * 2;

            f16x8 wvA[3][4], wvB[3][4]; float bIA[3], bIB[3];
#pragma unroll
            for (int T=0; T<3; T++){
#pragma unroll
                for (int kt=0; kt<4; kt++){
                    wvA[T][kt] = loadW8(Wih1 + (size_t)clsA[T]*kH + kt*32 + lq*8);
                    wvB[T][kt] = loadW8(Wih1 + (size_t)clsB[T]*kH + kt*32 + lq*8);
                }
                bIA[T] = bih1[clsA[T]];
                bIB[T] = bih1[clsB[T]];
            }
            const int sr = tid >> 4, sq = tid & 15;   // staging: row, 8-u32 chunk
            auto ld = [&](int t, uint4 &u0, uint4 &u1){
                const unsigned* p = h0r + ((size_t)(mb*kTc + t)*16 + sr)*kH + 8*sq;
                u0 = *(const uint4*)p; u1 = *(const uint4*)(p+4);
            };
            auto stage = [&](int bf, uint4 u0, uint4 u1){
                const unsigned us[8] = { u0.x,u0.y,u0.z,u0.w, u1.x,u1.y,u1.z,u1.w };
                f16x8 vh, vl;
#pragma unroll
                for (int j=0;j<8;j++){
                    vh[j] = u2f((unsigned short)(us[j]>>16));
                    vl[j] = u2f((unsigned short)us[j]);
                }
                *(f16x8*)&S.aH[bf][sr][8*sq] = vh;
                *(f16x8*)&S.aL[bf][sr][8*sq] = vl;
            };
            uint4 c0, c1, n0, n1;
            ld(t0, c0, c1);
            stage(0, c0, c1);
            ld(t0 + 1, n0, n1);
            bar_lds();
            for (int tt=0; tt<kTg; tt++){
                const int t = t0 + tt, bf = tt & 1;
                f16x8 fH[4], fL[4];
#pragma unroll
                for (int kt=0;kt<4;kt++){
                    fH[kt] = *(const f16x8*)&S.aH[bf][lm][kt*32 + lq*8];
                    fL[kt] = *(const f16x8*)&S.aL[bf][lm][kt*32 + lq*8];
                }
                if (tt+1 < kTg) stage(bf^1, n0, n1);
                if (tt+2 < kTg) ld(t0 + tt + 2, n0, n1);
                f32x4 aRA = {bIA[0],bIA[0],bIA[0],bIA[0]};
                f32x4 aZA = {bIA[1],bIA[1],bIA[1],bIA[1]};
                f32x4 aNA = {bIA[2],bIA[2],bIA[2],bIA[2]};
                f32x4 aRB = {bIB[0],bIB[0],bIB[0],bIB[0]};
                f32x4 aZB = {bIB[1],bIB[1],bIB[1],bIB[1]};
                f32x4 aNB = {bIB[2],bIB[2],bIB[2],bIB[2]};
#pragma unroll
                for (int kt=0;kt<4;kt++){
                    aRA=MFMA16(fH[kt],wvA[0][kt],aRA); aRA=MFMA16(fL[kt],wvA[0][kt],aRA);
                    aZA=MFMA16(fH[kt],wvA[1][kt],aZA); aZA=MFMA16(fL[kt],wvA[1][kt],aZA);
                    aNA=MFMA16(fH[kt],wvA[2][kt],aNA); aNA=MFMA16(fL[kt],wvA[2][kt],aNA);
                    aRB=MFMA16(fH[kt],wvB[0][kt],aRB); aRB=MFMA16(fL[kt],wvB[0][kt],aRB);
                    aZB=MFMA16(fH[kt],wvB[1][kt],aZB); aZB=MFMA16(fL[kt],wvB[1][kt],aZB);
                    aNB=MFMA16(fH[kt],wvB[2][kt],aNB); aNB=MFMA16(fL[kt],wvB[2][kt],aNB);
                }
                // store per-consumer-lane packed in the OLD tid slot space
                const size_t slotA = ((size_t)mb*kTc + t)*512 + 128*w + l;
                const size_t slotB = slotA + 64;
                *(uint4*)(gA + slotA*4) = make_uint4(pack2(aRA[0],aRA[1]), pack2(aRA[2],aRA[3]),
                                                     pack2(aZA[0],aZA[1]), pack2(aZA[2],aZA[3]));
                *(uint2*)(gB + slotA*2) = make_uint2(pack2(aNA[0],aNA[1]), pack2(aNA[2],aNA[3]));
                *(uint4*)(gA + slotB*4) = make_uint4(pack2(aRB[0],aRB[1]), pack2(aRB[2],aRB[3]),
                                                     pack2(aZB[0],aZB[1]), pack2(aZB[2],aZB[3]));
                *(uint2*)(gB + slotB*2) = make_uint2(pack2(aNB[0],aNB[1]), pack2(aNB[2],aNB[3]));
                bar_lds();
            }
        }
        // ---- gx0 phase: layer-0 input gates for chunk p=c+1, f32, exact ----
        const int p = c + 1;
        if (p >= 0 && p < kNCh) {
            unsigned* g0w = gx0 + (size_t)(p & 1) * kGx0Str;
            f16x8 xwA[3], xwB[3];
#pragma unroll
            for (int T=0; T<3; T++){
                xwA[T] = loadW8(Wih0 + (size_t)clsA[T]*48 + lq*8);
                xwB[T] = loadW8(Wih0 + (size_t)clsB[T]*48 + lq*8);
            }
            float iniA[3][4], iniB[3][4];
            {
#pragma unroll
                for (int q=0; q<4; q++){
                    const float* ep = embed + (size_t)tick[b0 + lq*4 + q] * kE;
#pragma unroll
                    for (int T=0; T<3; T++){
                        const float* wA = Wih0 + (size_t)clsA[T]*48 + 32;
                        const float* wB = Wih0 + (size_t)clsB[T]*48 + 32;
                        float sA=0.f, sB=0.f;
#pragma unroll
                        for (int e=0; e<kE; e++){
                            float ev = ep[e];
                            sA = fmaf(ev, wA[e], sA);
                            sB = fmaf(ev, wB[e], sB);
                        }
                        iniA[T][q] = bih0[clsA[T]] + sA;
                        iniB[T][q] = bih0[clsB[T]] + sB;
                    }
                }
            }
            // each wave loads the shared x A-fragment directly (rows lm,
            // cols lq*8..+7): 32B/lane, identical across waves -> cache hit
            for (int tt=0; tt<kTg; tt++){
                const int t = t0 + tt;
                const float* xp = x + (size_t)(b0+lm)*kT*kF + (size_t)(p*kTc + t)*kF + lq*8;
                const float4 xa = *(const float4*)xp;
                const float4 xb = *(const float4*)(xp + 4);
                const float xv[8] = { xa.x, xa.y, xa.z, xa.w, xb.x, xb.y, xb.z, xb.w };
                f16x8 xH, xL;
#pragma unroll
                for (int j=0;j<8;j++){
                    _Float16 hh,hl; splitF(xv[j],hh,hl);
                    xH[j]=hh; xL[j]=hl;
                }
                f32x4 aRA = {iniA[0][0],iniA[0][1],iniA[0][2],iniA[0][3]};
                f32x4 aZA = {iniA[1][0],iniA[1][1],iniA[1][2],iniA[1][3]};
                f32x4 aNA = {iniA[2][0],iniA[2][1],iniA[2][2],iniA[2][3]};
                f32x4 aRB = {iniB[0][0],iniB[0][1],iniB[0][2],iniB[0][3]};
                f32x4 aZB = {iniB[1][0],iniB[1][1],iniB[1][2],iniB[1][3]};
                f32x4 aNB = {iniB[2][0],iniB[2][1],iniB[2][2],iniB[2][3]};
                aRA=MFMA16(xH,xwA[0],aRA); aRA=MFMA16(xL,xwA[0],aRA);
                aZA=MFMA16(xH,xwA[1],aZA); aZA=MFMA16(xL,xwA[1],aZA);
                aNA=MFMA16(xH,xwA[2],aNA); aNA=MFMA16(xL,xwA[2],aNA);
                aRB=MFMA16(xH,xwB[0],aRB); aRB=MFMA16(xL,xwB[0],aRB);
                aZB=MFMA16(xH,xwB[1],aZB); aZB=MFMA16(xL,xwB[1],aZB);
                aNB=MFMA16(xH,xwB[2],aNB); aNB=MFMA16(xL,xwB[2],aNB);
                const size_t slotA = ((size_t)mb*kTc + t)*512 + 128*w + l;
                const size_t slotB = slotA + 64;
                *(uint4*)(g0w + slotA*12)     = __builtin_bit_cast(uint4, aRA);
                *(uint4*)(g0w + slotA*12 + 4) = __builtin_bit_cast(uint4, aZA);
                *(uint4*)(g0w + slotA*12 + 8) = __builtin_bit_cast(uint4, aNA);
                *(uint4*)(g0w + slotB*12)     = __builtin_bit_cast(uint4, aRB);
                *(uint4*)(g0w + slotB*12 + 4) = __builtin_bit_cast(uint4, aZB);
                *(uint4*)(g0w + slotB*12 + 8) = __builtin_bit_cast(uint4, aNB);
            }
        }
    } else {
        // ================= layer-1 recurrence, chunk e0=c-2 =================
        const int e0 = c - 2;
        if (e0 < 0 || e0 >= kNCh) return;
        SRec &S = sm.r;
        const int mb = blockIdx.x - 192, b0 = mb * kMB;
        const unsigned* gA = gxA + (size_t)(e0 & 1) * kSlots * 4;
        const unsigned* gB = gxB + (size_t)(e0 & 1) * kSlots * 2;

        f16x8 wvA[3][4], wvB[3][4];
#pragma unroll
        for (int T=0; T<3; T++)
#pragma unroll
            for (int kt=0; kt<4; kt++){
                wvA[T][kt] = loadW8(Whh1 + (size_t)clsA[T]*kH + kt*32 + lq*8);
                wvB[T][kt] = loadW8(Whh1 + (size_t)clsB[T]*kH + kt*32 + lq*8);
            }
        const float brA = bhh1[clsA[0]], bzA = bhh1[clsA[1]], bnA = bhh1[clsA[2]];
        const float brB = bhh1[clsB[0]], bzB = bhh1[clsB[1]], bnB = bhh1[clsB[2]];

        float hregA[4], hregB[4];
        if (e0 == 0){
#pragma unroll
            for (int q=0;q<4;q++){
                hregA[q]=0.f; hregB[q]=0.f;
                S.hH[0][lq*4+q][iA]=(_Float16)0.f; S.hL[0][lq*4+q][iA]=(_Float16)0.f;
                S.hH[0][lq*4+q][iB]=(_Float16)0.f; S.hL[0][lq*4+q][iB]=(_Float16)0.f;
            }
        } else {
#pragma unroll
            for (int q=0;q<4;q++){
                float hA = h1state[(size_t)(b0 + lq*4+q)*kH + iA];
                float hB = h1state[(size_t)(b0 + lq*4+q)*kH + iB];
                hregA[q]=hA; hregB[q]=hB;
                _Float16 hh,hl;
                splitF(hA,hh,hl); S.hH[0][lq*4+q][iA]=hh; S.hL[0][lq*4+q][iA]=hl;
                splitF(hB,hh,hl); S.hH[0][lq*4+q][iB]=hh; S.hL[0][lq*4+q][iB]=hl;
            }
        }
        // gx stream for both tiles, prefetched one step ahead
        const size_t s0 = (size_t)mb*kTc*512 + 128*w + l;
        const size_t s1 = s0 + 64;
        auto ld2 = [&](size_t slot){
            G2 g;
            g.a = *(const uint4*)(gA + slot*4);
            g.b = *(const uint2*)(gB + slot*2);
            return g;
        };
        G2 cA = ld2(s0), cB = ld2(s1), nA = ld2(s0+512), nB = ld2(s1+512);
        bar_lds();

        int buf = 0;
        for (int tc=0; tc<kTc; tc++){
            const int nb = buf ^ 1;
            f16x8 aHf[4], aLf[4];
#pragma unroll
            for (int kt=0;kt<4;kt++){
                aHf[kt] = *(const f16x8*)&S.hH[buf][lm][kt*32 + lq*8];
                aLf[kt] = *(const f16x8*)&S.hL[buf][lm][kt*32 + lq*8];
            }
            f32x4 aRA={brA,brA,brA,brA}, aZA={bzA,bzA,bzA,bzA}, aNA={bnA,bnA,bnA,bnA};
            f32x4 aRB={brB,brB,brB,brB}, aZB={bzB,bzB,bzB,bzB}, aNB={bnB,bnB,bnB,bnB};
#pragma unroll
            for (int kt=0;kt<4;kt++){
                aRA=MFMA16(aHf[kt],wvA[0][kt],aRA); aRA=MFMA16(aLf[kt],wvA[0][kt],aRA);
                aZA=MFMA16(aHf[kt],wvA[1][kt],aZA); aZA=MFMA16(aLf[kt],wvA[1][kt],aZA);
                aNA=MFMA16(aHf[kt],wvA[2][kt],aNA); aNA=MFMA16(aLf[kt],wvA[2][kt],aNA);
                aRB=MFMA16(aHf[kt],wvB[0][kt],aRB); aRB=MFMA16(aLf[kt],wvB[0][kt],aRB);
                aZB=MFMA16(aHf[kt],wvB[1][kt],aZB); aZB=MFMA16(aLf[kt],wvB[1][kt],aZB);
                aNB=MFMA16(aHf[kt],wvB[2][kt],aNB); aNB=MFMA16(aLf[kt],wvB[2][kt],aNB);
            }
#pragma unroll
            for (int q=0;q<4;q++){
                const float rx[4] = { (float)u2f((unsigned short)cA.a.x), (float)u2f((unsigned short)(cA.a.x>>16)),
                                      (float)u2f((unsigned short)cA.a.y), (float)u2f((unsigned short)(cA.a.y>>16)) };
                const float zx[4] = { (float)u2f((unsigned short)cA.a.z), (float)u2f((unsigned short)(cA.a.z>>16)),
                                      (float)u2f((unsigned short)cA.a.w), (float)u2f((unsigned short)(cA.a.w>>16)) };
                const float nx[4] = { (float)u2f((unsigned short)cA.b.x), (float)u2f((unsigned short)(cA.b.x>>16)),
                                      (float)u2f((unsigned short)cA.b.y), (float)u2f((unsigned short)(cA.b.y>>16)) };
                float r = sigm_hw(aRA[q] + rx[q]);
                float z = sigm_hw(aZA[q] + zx[q]);
                float n = tanh_hw(fmaf(r, aNA[q], nx[q]));
                float h = fmaf(z, hregA[q]-n, n);
                hregA[q] = h;
                _Float16 hh,hl; splitF(h,hh,hl);
                S.hH[nb][lq*4+q][iA]=hh; S.hL[nb][lq*4+q][iA]=hl;
            }
#pragma unroll
            for (int q=0;q<4;q++){
                const float rx[4] = { (float)u2f((unsigned short)cB.a.x), (float)u2f((unsigned short)(cB.a.x>>16)),
                                      (float)u2f((unsigned short)cB.a.y), (float)u2f((unsigned short)(cB.a.y>>16)) };
                const float zx[4] = { (float)u2f((unsigned short)cB.a.z), (float)u2f((unsigned short)(cB.a.z>>16)),
                                      (float)u2f((unsigned short)cB.a.w), (float)u2f((unsigned short)(cB.a.w>>16)) };
                const float nx[4] = { (float)u2f((unsigned short)cB.b.x), (float)u2f((unsigned short)(cB.b.x>>16)),
                                      (float)u2f((unsigned short)cB.b.y), (float)u2f((unsigned short)(cB.b.y>>16)) };
                float r = sigm_hw(aRB[q] + rx[q]);
                float z = sigm_hw(aZB[q] + zx[q]);
                float n = tanh_hw(fmaf(r, aNB[q], nx[q]));
                float h = fmaf(z, hregB[q]-n, n);
                hregB[q] = h;
                _Float16 hh,hl; splitF(h,hh,hl);
                S.hH[nb][lq*4+q][iB]=hh; S.hL[nb][lq*4+q][iB]=hl;
            }
            cA = nA; cB = nB;
            int tn = tc + 2; if (tn > kTc-1) tn = kTc-1;
            nA = ld2(s0 + (size_t)tn*512);
            nB = ld2(s1 + (size_t)tn*512);
            bar_lds();
            buf = nb;
        }
#pragma unroll
        for (int q=0;q<4;q++){
            h1state[(size_t)(b0 + lq*4+q)*kH + iA] = hregA[q];
            h1state[(size_t)(b0 + lq*4+q)*kH + iB] = hregB[q];
        }
        if (e0 == kNCh-1){
            // head: hid = relu(h1 @ hw1^T + hb1); y = hid @ hw2^T + hb2
#pragma unroll
            for (int q=0;q<4;q++){
                S.hf[lq*4+q][iA] = hregA[q];
                S.hf[lq*4+q][iB] = hregB[q];
            }
            __syncthreads();
            const int hm = tid >> 4, i0 = (tid & 15) * 8;
#pragma unroll
            for (int e=0;e<8;e++){
                const float* wr = hw1 + (size_t)(i0+e)*kH;
                float s = hb1[i0+e];
                for (int k2=0;k2<kH;k2++) s = fmaf(wr[k2], S.hf[hm][k2], s);
                S.hf2[hm][i0+e] = fmaxf(s, 0.f);
            }
            __syncthreads();
            if (tid < kMB){
                float s = hb2[0];
                for (int k2=0;k2<kH;k2++) s = fmaf(S.hf2[tid][k2], hw2[k2], s);
                out[b0 + tid] = s;
            }
        }
    }
}

extern "C" void kernel_launch(void* const* d_in, const int* in_sizes, int n_in,
                              void* d_out, int out_size, void* d_ws, size_t ws_size,
                              hipStream_t stream)
{
    const float* x     = (const float*)d_in[0];
    const int*   tick  = (const int*)d_in[1];
    const float* embed = (const float*)d_in[2];
    const float* Wih0  = (const float*)d_in[3];
    const float* Whh0  = (const float*)d_in[4];
    const float* bih0  = (const float*)d_in[5];
    const float* bhh0  = (const float*)d_in[6];
    const float* Wih1  = (const float*)d_in[7];
    const float* Whh1  = (const float*)d_in[8];
    const float* bih1  = (const float*)d_in[9];
    const float* bhh1  = (const float*)d_in[10];
    const float* hw1   = (const float*)d_in[11];
    const float* hb1   = (const float*)d_in[12];
    const float* hw2   = (const float*)d_in[13];
    const float* hb2   = (const float*)d_in[14];
    float* out = (float*)d_out;

    // ws: h0seq 2x16.8MB | gxA 2x16.8MB | gxB 2x8.4MB | h1state 0.5MB |
    //     gx0 2x50.3MB  ~ 185MB total
    unsigned* h0seq = (unsigned*)d_ws;
    unsigned* gxA   = h0seq + 2*kH0Str;
    unsigned* gxB   = gxA + 2*kSlots*4;
    float*  h1state = (float*)(gxB + 2*kSlots*2);
    unsigned* gx0   = (unsigned*)(h1state + (size_t)kB*kH);

    for (int c = -1; c <= kNCh + 1; c++){
        rnn_fused<<<256, 256, 0, stream>>>(x, tick, embed,
            Wih0, Whh0, bih0, bhh0, Wih1, bih1, Whh1, bhh1,
            hw1, hb1, hw2, hb2, h0seq, gxA, gxB, h1state, gx0, out, c);
    }
}